// Round 5
// baseline (148.258 us; speedup 1.0000x reference)
//
#include <hip/hip_runtime.h>

#define TWO_PI_F 6.283185307179586f
#define EPS_F 1e-6f
#define LOG2E_F 1.4426950408889634f
#define BATCH 32

// Bare v_exp_f32 (2^x). libm exp2f wraps it with edge-case fixups (round-11
// measured: -11 us on layer 2 from dropping the wrapper).
#if __has_builtin(__builtin_amdgcn_exp2f)
#define EXP2F(x) __builtin_amdgcn_exp2f(x)
#else
#define EXP2F(x) exp2f(x)
#endif

typedef float v2f __attribute__((ext_vector_type(2)));

// Replace non-finite by 0 (bit test so fast-math can't fold it away).
__device__ __forceinline__ float sane(float x) {
    return ((__float_as_uint(x) & 0x7f800000u) == 0x7f800000u) ? 0.f : x;
}

// ============================================================================
// Round-17 experiment: ONE code image for L1 and L2 (runtime geometry) so
// L2 rides the I-cache lines L1 already pulled through the poisoned-cold
// cache hierarchy. Theory: ~35 us of each 41-us layer dispatch is cold
// instruction fetch (work-independent: L1 @ 20 Phase-B iters == L2 @ 79;
// fillBuffer shows ~0 per-dispatch overhead, so the constant is in OUR code).
// Numerics: G/CHUNK/group order/reduce order EXACTLY as round-4 -> bit-exact.
// KP=5 static (register structure); TPG passed as log2. Poly table padded
// per-group to CHUNKP (mult of 4) with zero rows: consumed pad row adds
// fma(+0,1,acc) = acc.  L3 stays on the old KP=6 template as a CONTROL.
// ============================================================================
__global__ __launch_bounds__(1024) void layer_unified(
    const float* __restrict__ in_x,            // first: (B,1,64,7) f32
    const float* __restrict__ prev_sel,        // !first: (B,LI,ND,7) f32
    const float* __restrict__ prev_tot,        // !first: (B,LI) f32
    const float* __restrict__ kern,            // (LO,LI,NK,7) f32
    const float* __restrict__ bias,            // (LO,) f32
    float* __restrict__ out_sel,               // (B,LO,KOUT,7) f32
    float* __restrict__ out_tot,               // (B,LO) f32
    const int LO, const int LI, const int ND, const int NK,
    const int NCOMP, const int KOUT,
    const int TPGL,                            // log2(TPG): 6 or 7
    const int G, const int CHUNK, const int CHUNKP,  // CHUNKP = 4-aligned
    const int KUSE, const int first)
{
    constexpr int KP = 5, NT = 1024, NPAIR = 2;
    // Max-capacity LDS (covers L1 and L2 geometries)
    constexpr int M_NCOMP = 625, M_NCOMP4 = 628, M_NPADT = 8*80 + 4; // 644
    constexpr int M_ACC   = 5120;      // G*TPG*KP floats (both layers = 5120)
    struct StageT {
        float4 d_c[125];
        float4 k_c[25];
        float  d_w[125], d_px[125], d_py[125];
        float  k_w[25],  k_px[25],  k_py[25];
    };
    constexpr size_t ACCB = (size_t)M_ACC * sizeof(float);
    constexpr size_t UB   = sizeof(StageT) > ACCB ? sizeof(StageT) : ACCB;
    __shared__ __align__(16) unsigned char u_smem[UB];
    StageT& st    = *reinterpret_cast<StageT*>(u_smem);
    float* accbuf = reinterpret_cast<float*>(u_smem);

    __shared__ float2 cPos[M_NCOMP];
    __shared__ float4 nP[M_NPADT];
    __shared__ float4 nQ[M_NPADT];
    __shared__ float4 cC[M_NCOMP];
    __shared__ float  w2s[M_NCOMP];
    __shared__ __align__(16) float a2s[M_NCOMP4];
    __shared__ __align__(16) float scr[64];
    __shared__ float  selint[32];
    __shared__ float  dscale[8];
    __shared__ float  ptot[BATCH*5];

    const int b   = blockIdx.x / LO;
    const int lo  = blockIdx.x - b*LO;
    const int tid = threadIdx.x;
    const int tpg = 1 << TPGL;
    const int g   = tid >> TPGL;
    const int kt  = tid & (tpg - 1);
    const bool active = (kt < KUSE);
    const int NQn = (NCOMP + 3) >> 2;
    const int NCOMP4 = NQn << 2;
    const int NPADT = G*CHUNKP + 4;

    // ---- Phase pre: incoming batchnorm + stage data/kernel into LDS
    if (first) {
        if (tid < ND) {
            const float* s = in_x + (size_t)(b*ND + tid)*7;
            const float w  = sane(s[0]);
            const float c0 = sane(s[3]), c1 = sane(s[4]), c2 = sane(s[5]), c3 = sane(s[6]);
            st.d_w[tid] = w; st.d_px[tid] = sane(s[1]); st.d_py[tid] = sane(s[2]);
            st.d_c[tid] = make_float4(c0, c1, c2, c3);
            const float det = c0*c3 - c1*c2;
            scr[tid] = sane(fabsf(w) * TWO_PI_F * sqrtf(fmaxf(det, EPS_F)));
        }
        __syncthreads();
        if (tid == 0) {
            // float4 reads, scalar adds left-to-right (order == reference)
            float s = 0.f;
            const float4* s4 = (const float4*)scr;
            const int nq = ND >> 2;
            for (int i = 0; i < nq; ++i) {
                const float4 v = s4[i];
                s += v.x; s += v.y; s += v.z; s += v.w;
            }
            dscale[0] = 1.f / (s + EPS_F);
        }
        __syncthreads();
        if (tid < ND) st.d_w[tid] = sane(st.d_w[tid] * dscale[0]);
    } else {
        // Cooperative coalesced stage of prev_tot, then order-preserving sum.
        for (int i = tid; i < BATCH*LI; i += NT) ptot[i] = prev_tot[i];
        __syncthreads();
        if (tid < LI) {
            float s = 0.f;
            #pragma unroll 1
            for (int bb = 0; bb < BATCH; ++bb) s += ptot[bb*LI + tid];
            dscale[tid] = 1.f / (s / (float)BATCH + EPS_F);
        }
        __syncthreads();
        if (tid < LI*ND) {
            const int li = tid / ND;
            const float* s = prev_sel + (size_t)(b*LI*ND + tid)*7;
            st.d_w[tid]  = sane(s[0] * dscale[li]);
            st.d_px[tid] = s[1]; st.d_py[tid] = s[2];
            st.d_c[tid]  = make_float4(s[3], s[4], s[5], s[6]);
        }
    }
    if (tid < LI*NK) {
        const float* s = kern + (size_t)(lo*LI*NK + tid)*7;
        st.k_w[tid]  = sane(s[0]);
        st.k_px[tid] = sane(s[1]); st.k_py[tid] = sane(s[2]);
        st.k_c[tid]  = make_float4(sane(s[3]), sane(s[4]), sane(s[5]), sane(s[6]));
    }
    // Zero the pad rows of the per-group-strided poly table (slots >= CHUNK,
    // comps >= NCOMP, and the +4 prefetch tail). Disjoint from Phase-A rows.
    for (int r = tid; r < NPADT; r += NT) {
        const int gg = r / CHUNKP;
        const int ss = r - gg*CHUNKP;
        const bool valid = (gg < G) && (ss < CHUNK) && (gg*CHUNK + ss < NCOMP);
        if (!valid) {
            nP[r] = make_float4(0.f, 0.f, 0.f, 0.f);
            nQ[r] = make_float4(0.f, 0.f, 0.f, 0.f);
        }
    }
    __syncthreads();

    // ---- Phase A: gm_convolve -> poly coefficients in LDS.
    // Flattening matches reference reshape: (li, nd, nk), nk fastest.
    // Table row remap: comp -> (comp/CHUNK)*CHUNKP + comp%CHUNK.
    if (tid < NCOMP) {
        const int li = tid / (ND*NK);
        const int r  = tid - li*(ND*NK);
        const int nd = r / NK, nk = r - (r/NK)*NK;
        const int di = li*ND + nd, ki = li*NK + nk;
        const float4 dc = st.d_c[di], kc = st.k_c[ki];
        const float c0 = dc.x + kc.x, c1 = dc.y + kc.y, c2 = dc.z + kc.z, c3 = dc.w + kc.w;
        const float dd = dc.x*dc.w - dc.y*dc.z;
        const float dk = kc.x*kc.w - kc.y*kc.z;
        const float ds = c0*c3 - c1*c2;
        const float w  = sane(st.d_w[di]*st.k_w[ki]*TWO_PI_F*sqrtf(fmaxf(dd*dk, 0.f) / fmaxf(ds, EPS_F)));
        const float px = sane(st.d_px[di] + st.k_px[ki]);
        const float py = sane(st.d_py[di] + st.k_py[ki]);
        const float inv = -0.5f * LOG2E_F / ds;
        const float a   = sane(c3*inv);
        const float bb  = sane(-(c1 + c2)*inv);
        const float cc  = sane(c0*inv);
        const float dd2 = sane(-(2.f*a*px + bb*py));
        const float ee  = sane(-(2.f*cc*py + bb*px));
        const float ff  = sane((a*px + bb*py)*px + cc*py*py);
        const int grp = tid / CHUNK;
        const int row = grp*CHUNKP + (tid - grp*CHUNK);
        cPos[tid] = make_float2(px, py);
        nP[row]   = make_float4(a, bb, cc, dd2);
        nQ[row]   = make_float4(ee, ff, w, 0.f);
        cC[tid]   = make_float4(sane(c0), sane(c1), sane(c2), sane(c3));
    }
    __syncthreads();

    // ---- Phase B: eval_at_centers. k-slots paired (v_pk_fma_f32); per-n LDS
    // broadcast software-pipelined 4 deep with named registers. Consumption
    // order within each group = ascending real rows (+ trailing zero rows:
    // fma(+0,1,acc) bit-neutral) -> bit-exact accumulation.
    v2f kxP[NPAIR], kyP[NPAIR], kx2P[NPAIR], ky2P[NPAIR], kxyP[NPAIR], accP[NPAIR];
    float kxS = 0.f, kyS = 0.f, kx2S = 0.f, ky2S = 0.f, kxyS = 0.f, accS = 0.f;
    #pragma unroll
    for (int p = 0; p < NPAIR; ++p) {
        float x0 = 0.f, y0 = 0.f, x1 = 0.f, y1 = 0.f;
        if (active) {
            const float2 p0 = cPos[kt + (2*p    )*KUSE];
            const float2 p1 = cPos[kt + (2*p + 1)*KUSE];
            x0 = p0.x; y0 = p0.y; x1 = p1.x; y1 = p1.y;
        }
        v2f kx; kx.x = x0; kx.y = x1;
        v2f ky; ky.x = y0; ky.y = y1;
        kxP[p] = kx; kyP[p] = ky;
        kx2P[p] = kx*kx; ky2P[p] = ky*ky; kxyP[p] = kx*ky;
        v2f z; z.x = 0.f; z.y = 0.f; accP[p] = z;
    }
    {   // odd slot (KP=5)
        if (active) { const float2 pz = cPos[kt + (KP-1)*KUSE]; kxS = pz.x; kyS = pz.y; }
        kx2S = kxS*kxS; ky2S = kyS*kyS; kxyS = kxS*kyS;
    }
    {
        const float4* __restrict__ bP = &nP[g*CHUNKP];
        const float4* __restrict__ bQ = &nQ[g*CHUNKP];
        float4 P0 = bP[0], Q0 = bQ[0];
        float4 P1 = bP[1], Q1 = bQ[1];
        float4 P2 = bP[2], Q2 = bQ[2];
        float4 P3 = bP[3], Q3 = bQ[3];
        int nr = 4;   // pad rows make bP[CHUNKP..CHUNKP+3] safe for last group
        const int quads = CHUNKP >> 2;

#define PHB_STEP(PP,QQ)                                                       \
        {   const float4 Pn_ = bP[nr], Qn_ = bQ[nr]; ++nr;                    \
            v2f Pa; Pa.x = PP.x; Pa.y = PP.x;                                 \
            v2f Pb; Pb.x = PP.y; Pb.y = PP.y;                                 \
            v2f Pc; Pc.x = PP.z; Pc.y = PP.z;                                 \
            v2f Pd; Pd.x = PP.w; Pd.y = PP.w;                                 \
            v2f Qe; Qe.x = QQ.x; Qe.y = QQ.x;                                 \
            v2f Qf; Qf.x = QQ.y; Qf.y = QQ.y;                                 \
            v2f Qw; Qw.x = QQ.z; Qw.y = QQ.z;                                 \
            _Pragma("unroll")                                                 \
            for (int p = 0; p < NPAIR; ++p) {                                 \
                const v2f md = __builtin_elementwise_fma(Pa, kx2P[p],         \
                               __builtin_elementwise_fma(Pb, kxyP[p],         \
                               __builtin_elementwise_fma(Pc, ky2P[p],         \
                               __builtin_elementwise_fma(Pd, kxP[p],          \
                               __builtin_elementwise_fma(Qe, kyP[p], Qf)))));  \
                v2f ex; ex.x = EXP2F(md.x); ex.y = EXP2F(md.y);               \
                accP[p] = __builtin_elementwise_fma(Qw, ex, accP[p]);         \
            }                                                                 \
            {                                                                 \
                const float md = fmaf(PP.x, kx2S,                             \
                                 fmaf(PP.y, kxyS,                             \
                                 fmaf(PP.z, ky2S,                             \
                                 fmaf(PP.w, kxS,                              \
                                 fmaf(QQ.x, kyS, QQ.y)))));                   \
                accS = fmaf(QQ.z, EXP2F(md), accS);                           \
            }                                                                 \
            PP = Pn_; QQ = Qn_; }

        #pragma unroll 1
        for (int i4 = 0; i4 < quads; ++i4) {
            PHB_STEP(P0, Q0)
            PHB_STEP(P1, Q1)
            PHB_STEP(P2, Q2)
            PHB_STEP(P3, Q3)
        }
#undef PHB_STEP
    }
    // Unpack pairs back to per-slot acc[]
    float acc[KP];
    #pragma unroll
    for (int p = 0; p < NPAIR; ++p) { acc[2*p] = accP[p].x; acc[2*p+1] = accP[p].y; }
    acc[KP-1] = accS;

    // ALL groups publish partials; reduce is then fully parallel.
    if (active) {
        #pragma unroll
        for (int j = 0; j < KP; ++j) accbuf[(g*tpg + kt)*KP + j] = acc[j];
    }
    __syncthreads();

    // ---- Phase R: per-component G-way sum (ascending g == round-4 order,
    // bit-exact) + bias + relu_fit scale. One thread per component.
    const float bi = bias[lo];
    if (tid < NCOMP) {
        const int j2  = tid / KUSE;
        const int kt2 = tid - j2*KUSE;
        float s = accbuf[kt2*KP + j2];
        #pragma unroll 1
        for (int g2 = 1; g2 < G; ++g2) s += accbuf[(g2*tpg + kt2)*KP + j2];
        const float v  = s + bi;
        const float sc = fmaxf(v, 0.f) / (fabsf(v) + EPS_F);
        const int grp = tid / CHUNK;
        const int row = grp*CHUNKP + (tid - grp*CHUNK);
        const float ww = sane(nQ[row].z * sc);
        w2s[tid] = ww;
        a2s[tid] = fabsf(ww);
    }
    for (int i = NCOMP + tid - (tid < NCOMP ? tid : tid); false;) {}  // (no-op)
    if (tid >= NCOMP && tid < NCOMP4) a2s[tid] = -1.f;  // pad: never ranks
    __syncthreads();

    // ---- Phase C: stable-descending rank (== jax.lax.top_k order), group-split
    const int CQ = (NQn + G - 1) / G;
    int rank[KP];
    float myv[KP];
    #pragma unroll
    for (int j = 0; j < KP; ++j) rank[j] = 0;
    if (active) {
        #pragma unroll
        for (int j = 0; j < KP; ++j) myv[j] = a2s[kt + j*KUSE];
        const int q0 = g*CQ;
        const int q1 = (q0 + CQ < NQn) ? (q0 + CQ) : NQn;
        #pragma unroll 1
        for (int q = q0; q < q1; ++q) {
            const float4 v4 = ((const float4*)a2s)[q];  // broadcast
            #pragma unroll
            for (int c = 0; c < 4; ++c) {
                const float vj = (c == 0) ? v4.x : (c == 1) ? v4.y : (c == 2) ? v4.z : v4.w;
                const int   jj = 4*q + c;
                #pragma unroll
                for (int j = 0; j < KP; ++j) {
                    const int myk = kt + j*KUSE;
                    rank[j] += (vj > myv[j] || (vj == myv[j] && jj < myk)) ? 1 : 0;
                }
            }
        }
        // rank partials (ints, <= 625 -> exact in f32) from ALL groups
        #pragma unroll
        for (int j = 0; j < KP; ++j) accbuf[(g*tpg + kt)*KP + j] = (float)rank[j];
    }
    __syncthreads();

    // ---- Phase D: per-component rank finalize + select + write (parallel).
    if (tid < NCOMP) {
        const int j2  = tid / KUSE;
        const int kt2 = tid - j2*KUSE;
        int r = 0;
        #pragma unroll 1
        for (int g2 = 0; g2 < G; ++g2) r += (int)accbuf[(g2*tpg + kt2)*KP + j2];
        if (r < KOUT) {
            const float2 p = cPos[tid];
            const float4 c = cC[tid];
            const float ww = w2s[tid];
            float* dst = out_sel + (size_t)((b*LO + lo)*KOUT + r)*7;
            dst[0] = ww; dst[1] = p.x; dst[2] = p.y;
            dst[3] = c.x; dst[4] = c.y; dst[5] = c.z; dst[6] = c.w;
            const float det = c.x*c.w - c.y*c.z;
            selint[r] = sane(fabsf(ww) * TWO_PI_F * sqrtf(fmaxf(det, EPS_F)));
        }
    }
    __syncthreads();
    if (tid == 0) {
        float s = 0.f;
        #pragma unroll 1
        for (int i = 0; i < KOUT; ++i) s += selint[i];
        out_tot[b*LO + lo] = s;
    }
}

// ============================================================================
// Old monolithic template: retained ONLY for L3 (KP=6) as the round-5 control.
// Byte-identical structure to round 4.
// ============================================================================
template<int LO, int LI, int ND, int NK, int NCOMP, int KOUT,
         int KP, int TPG, int G, bool FIRST>
__global__ __launch_bounds__(TPG*G) void layer_kernel(
    const float* __restrict__ in_x,
    const float* __restrict__ prev_sel,
    const float* __restrict__ prev_tot,
    const float* __restrict__ kern,
    const float* __restrict__ bias,
    float* __restrict__ out_sel,
    float* __restrict__ out_tot)
{
    constexpr int KUSE   = NCOMP / KP;
    static_assert(KUSE * KP == NCOMP, "exact k tiling required");
    constexpr int NT     = TPG * G;
    static_assert(NT >= NCOMP, "one k per thread in reduce/select phases");
    constexpr int CHUNK  = (NCOMP + G - 1) / G;
    constexpr int NPADT  = G*CHUNK + 4;
    constexpr int NCOMP4 = (NCOMP + 3) & ~3;
    constexpr int NQn    = NCOMP4 / 4;
    constexpr int NPAIR  = KP / 2;
    constexpr int PPAD   = NPAIR > 0 ? NPAIR : 1;
    constexpr bool ODD   = (KP & 1) != 0;

    const int b   = blockIdx.x / LO;
    const int lo  = blockIdx.x % LO;
    const int tid = threadIdx.x;
    const int g   = tid / TPG;
    const int kt  = tid % TPG;
    const bool active = (kt < KUSE);

    struct StageT {
        float4 d_c[LI*ND];
        float4 k_c[LI*NK];
        float  d_w[LI*ND], d_px[LI*ND], d_py[LI*ND];
        float  k_w[LI*NK], k_px[LI*NK], k_py[LI*NK];
    };
    constexpr size_t ACCB = (size_t)G*TPG*KP * sizeof(float);
    constexpr size_t UB   = sizeof(StageT) > ACCB ? sizeof(StageT) : ACCB;
    __shared__ __align__(16) unsigned char u_smem[UB];
    StageT& st    = *reinterpret_cast<StageT*>(u_smem);
    float* accbuf = reinterpret_cast<float*>(u_smem);

    __shared__ float2 cPos[NCOMP];
    __shared__ float4 nP[NPADT];
    __shared__ float4 nQ[NPADT];
    __shared__ float4 cC[NCOMP];
    __shared__ float  w2s[NCOMP];
    __shared__ __align__(16) float a2s[NCOMP4];
    __shared__ __align__(16) float scr[64];
    __shared__ float  selint[32];
    __shared__ float  dscale[LI];
    __shared__ float  ptot[FIRST ? 1 : BATCH*LI];

    if constexpr (FIRST) {
        if (tid < ND) {
            const float* s = in_x + (size_t)(b*ND + tid)*7;
            const float w  = sane(s[0]);
            const float c0 = sane(s[3]), c1 = sane(s[4]), c2 = sane(s[5]), c3 = sane(s[6]);
            st.d_w[tid] = w; st.d_px[tid] = sane(s[1]); st.d_py[tid] = sane(s[2]);
            st.d_c[tid] = make_float4(c0, c1, c2, c3);
            const float det = c0*c3 - c1*c2;
            scr[tid] = sane(fabsf(w) * TWO_PI_F * sqrtf(fmaxf(det, EPS_F)));
        }
        __syncthreads();
        if (tid == 0) {
            float s = 0.f;
            const float4* s4 = (const float4*)scr;
            for (int i = 0; i < 16; ++i) {
                const float4 v = s4[i];
                s += v.x; s += v.y; s += v.z; s += v.w;
            }
            dscale[0] = 1.f / (s + EPS_F);
        }
        __syncthreads();
        if (tid < ND) st.d_w[tid] = sane(st.d_w[tid] * dscale[0]);
    } else {
        for (int i = tid; i < BATCH*LI; i += NT) ptot[i] = prev_tot[i];
        __syncthreads();
        if (tid < LI) {
            float s = 0.f;
            #pragma unroll 1
            for (int bb = 0; bb < BATCH; ++bb) s += ptot[bb*LI + tid];
            dscale[tid] = 1.f / (s / (float)BATCH + EPS_F);
        }
        __syncthreads();
        if (tid < LI*ND) {
            const int li = tid / ND;
            const float* s = prev_sel + (size_t)(b*LI*ND + tid)*7;
            st.d_w[tid]  = sane(s[0] * dscale[li]);
            st.d_px[tid] = s[1]; st.d_py[tid] = s[2];
            st.d_c[tid]  = make_float4(s[3], s[4], s[5], s[6]);
        }
    }
    if (tid < LI*NK) {
        const float* s = kern + (size_t)(lo*LI*NK + tid)*7;
        st.k_w[tid]  = sane(s[0]);
        st.k_px[tid] = sane(s[1]); st.k_py[tid] = sane(s[2]);
        st.k_c[tid]  = make_float4(sane(s[3]), sane(s[4]), sane(s[5]), sane(s[6]));
    }
    __syncthreads();

    if (tid < NCOMP) {
        const int li = tid / (ND*NK);
        const int r  = tid % (ND*NK);
        const int nd = r / NK, nk = r % NK;
        const int di = li*ND + nd, ki = li*NK + nk;
        const float4 dc = st.d_c[di], kc = st.k_c[ki];
        const float c0 = dc.x + kc.x, c1 = dc.y + kc.y, c2 = dc.z + kc.z, c3 = dc.w + kc.w;
        const float dd = dc.x*dc.w - dc.y*dc.z;
        const float dk = kc.x*kc.w - kc.y*kc.z;
        const float ds = c0*c3 - c1*c2;
        const float w  = sane(st.d_w[di]*st.k_w[ki]*TWO_PI_F*sqrtf(fmaxf(dd*dk, 0.f) / fmaxf(ds, EPS_F)));
        const float px = sane(st.d_px[di] + st.k_px[ki]);
        const float py = sane(st.d_py[di] + st.k_py[ki]);
        const float inv = -0.5f * LOG2E_F / ds;
        const float a   = sane(c3*inv);
        const float bb  = sane(-(c1 + c2)*inv);
        const float cc  = sane(c0*inv);
        const float dd2 = sane(-(2.f*a*px + bb*py));
        const float ee  = sane(-(2.f*cc*py + bb*px));
        const float ff  = sane((a*px + bb*py)*px + cc*py*py);
        cPos[tid] = make_float2(px, py);
        nP[tid]   = make_float4(a, bb, cc, dd2);
        nQ[tid]   = make_float4(ee, ff, w, 0.f);
        cC[tid]   = make_float4(sane(c0), sane(c1), sane(c2), sane(c3));
    }
    for (int i = NCOMP + tid; i < NPADT; i += NT) {
        nP[i] = make_float4(0.f, 0.f, 0.f, 0.f);
        nQ[i] = make_float4(0.f, 0.f, 0.f, 0.f);
    }
    __syncthreads();

    v2f kxP[PPAD], kyP[PPAD], kx2P[PPAD], ky2P[PPAD], kxyP[PPAD], accP[PPAD];
    float kxS = 0.f, kyS = 0.f, kx2S = 0.f, ky2S = 0.f, kxyS = 0.f, accS = 0.f;
    #pragma unroll
    for (int p = 0; p < NPAIR; ++p) {
        float x0 = 0.f, y0 = 0.f, x1 = 0.f, y1 = 0.f;
        if (active) {
            const float2 p0 = cPos[kt + (2*p    )*KUSE];
            const float2 p1 = cPos[kt + (2*p + 1)*KUSE];
            x0 = p0.x; y0 = p0.y; x1 = p1.x; y1 = p1.y;
        }
        v2f kx; kx.x = x0; kx.y = x1;
        v2f ky; ky.x = y0; ky.y = y1;
        kxP[p] = kx; kyP[p] = ky;
        kx2P[p] = kx*kx; ky2P[p] = ky*ky; kxyP[p] = kx*ky;
        v2f z; z.x = 0.f; z.y = 0.f; accP[p] = z;
    }
    if constexpr (ODD) {
        if (active) { const float2 pz = cPos[kt + (KP-1)*KUSE]; kxS = pz.x; kyS = pz.y; }
        kx2S = kxS*kxS; ky2S = kyS*kyS; kxyS = kxS*kyS;
    }
    {
        const int n0 = g*CHUNK;
        const float4* __restrict__ bP = &nP[n0];
        const float4* __restrict__ bQ = &nQ[n0];
        float4 P0 = bP[0], Q0 = bQ[0];
        float4 P1 = bP[1], Q1 = bQ[1];
        float4 P2 = bP[2], Q2 = bQ[2];
        float4 P3 = bP[3], Q3 = bQ[3];
        int nr = 4;

#define PHB_STEP(PP,QQ)                                                       \
        {   const float4 Pn_ = bP[nr], Qn_ = bQ[nr]; ++nr;                    \
            v2f Pa; Pa.x = PP.x; Pa.y = PP.x;                                 \
            v2f Pb; Pb.x = PP.y; Pb.y = PP.y;                                 \
            v2f Pc; Pc.x = PP.z; Pc.y = PP.z;                                 \
            v2f Pd; Pd.x = PP.w; Pd.y = PP.w;                                 \
            v2f Qe; Qe.x = QQ.x; Qe.y = QQ.x;                                 \
            v2f Qf; Qf.x = QQ.y; Qf.y = QQ.y;                                 \
            v2f Qw; Qw.x = QQ.z; Qw.y = QQ.z;                                 \
            _Pragma("unroll")                                                 \
            for (int p = 0; p < NPAIR; ++p) {                                 \
                const v2f md = __builtin_elementwise_fma(Pa, kx2P[p],         \
                               __builtin_elementwise_fma(Pb, kxyP[p],         \
                               __builtin_elementwise_fma(Pc, ky2P[p],         \
                               __builtin_elementwise_fma(Pd, kxP[p],          \
                               __builtin_elementwise_fma(Qe, kyP[p], Qf)))));  \
                v2f ex; ex.x = EXP2F(md.x); ex.y = EXP2F(md.y);               \
                accP[p] = __builtin_elementwise_fma(Qw, ex, accP[p]);         \
            }                                                                 \
            if constexpr (ODD) {                                              \
                const float md = fmaf(PP.x, kx2S,                             \
                                 fmaf(PP.y, kxyS,                             \
                                 fmaf(PP.z, ky2S,                             \
                                 fmaf(PP.w, kxS,                              \
                                 fmaf(QQ.x, kyS, QQ.y)))));                   \
                accS = fmaf(QQ.z, EXP2F(md), accS);                           \
            }                                                                 \
            PP = Pn_; QQ = Qn_; }

        #pragma unroll 1
        for (int i4 = 0; i4 < CHUNK/4; ++i4) {
            PHB_STEP(P0, Q0)
            PHB_STEP(P1, Q1)
            PHB_STEP(P2, Q2)
            PHB_STEP(P3, Q3)
        }
        if constexpr ((CHUNK % 4) >= 1) PHB_STEP(P0, Q0)
        if constexpr ((CHUNK % 4) >= 2) PHB_STEP(P1, Q1)
        if constexpr ((CHUNK % 4) >= 3) PHB_STEP(P2, Q2)
#undef PHB_STEP
    }
    float acc[KP];
    #pragma unroll
    for (int p = 0; p < NPAIR; ++p) { acc[2*p] = accP[p].x; acc[2*p+1] = accP[p].y; }
    if constexpr (ODD) acc[KP-1] = accS;

    if (active) {
        #pragma unroll
        for (int j = 0; j < KP; ++j) accbuf[(g*TPG + kt)*KP + j] = acc[j];
    }
    __syncthreads();

    const float bi = bias[lo];
    if (tid < NCOMP) {
        const int kt2 = tid % KUSE;
        const int j2  = tid / KUSE;
        float s = accbuf[(kt2)*KP + j2];
        #pragma unroll
        for (int g2 = 1; g2 < G; ++g2) s += accbuf[(g2*TPG + kt2)*KP + j2];
        const float v  = s + bi;
        const float sc = fmaxf(v, 0.f) / (fabsf(v) + EPS_F);
        const float ww = sane(nQ[tid].z * sc);
        w2s[tid] = ww;
        a2s[tid] = fabsf(ww);
    }
    if constexpr (NCOMP4 > NCOMP) {
        if (tid >= NCOMP && tid < NCOMP4) a2s[tid] = -1.f;
    }
    __syncthreads();

    constexpr int CQ = (NQn + G - 1) / G;
    int rank[KP];
    float myv[KP];
    #pragma unroll
    for (int j = 0; j < KP; ++j) rank[j] = 0;
    if (active) {
        #pragma unroll
        for (int j = 0; j < KP; ++j) myv[j] = a2s[kt + j*KUSE];
        const int q0 = g*CQ;
        const int q1 = (q0 + CQ < NQn) ? (q0 + CQ) : NQn;
        for (int q = q0; q < q1; ++q) {
            const float4 v4 = ((const float4*)a2s)[q];
            #pragma unroll
            for (int c = 0; c < 4; ++c) {
                const float vj = (c == 0) ? v4.x : (c == 1) ? v4.y : (c == 2) ? v4.z : v4.w;
                const int   jj = 4*q + c;
                #pragma unroll
                for (int j = 0; j < KP; ++j) {
                    const int myk = kt + j*KUSE;
                    rank[j] += (vj > myv[j] || (vj == myv[j] && jj < myk)) ? 1 : 0;
                }
            }
        }
        #pragma unroll
        for (int j = 0; j < KP; ++j) accbuf[(g*TPG + kt)*KP + j] = (float)rank[j];
    }
    __syncthreads();

    if (tid < NCOMP) {
        const int kt2 = tid % KUSE;
        const int j2  = tid / KUSE;
        int r = 0;
        #pragma unroll
        for (int g2 = 0; g2 < G; ++g2) r += (int)accbuf[(g2*TPG + kt2)*KP + j2];
        if (r < KOUT) {
            const float2 p = cPos[tid];
            const float4 c = cC[tid];
            const float ww = w2s[tid];
            float* dst = out_sel + (size_t)((b*LO + lo)*KOUT + r)*7;
            dst[0] = ww; dst[1] = p.x; dst[2] = p.y;
            dst[3] = c.x; dst[4] = c.y; dst[5] = c.z; dst[6] = c.w;
            const float det = c.x*c.w - c.y*c.z;
            selint[r] = sane(fabsf(ww) * TWO_PI_F * sqrtf(fmaxf(det, EPS_F)));
        }
    }
    __syncthreads();
    if (tid == 0) {
        float s = 0.f;
        for (int i = 0; i < KOUT; ++i) s += selint[i];
        out_tot[b*LO + lo] = s;
    }
}

// Final: batchnorm3 scale (mean over batch) -> integrate -> log_softmax -> f32
__global__ __launch_bounds__(64) void final_kernel(
    const float* __restrict__ sel3,   // (B,10,5,7)
    const float* __restrict__ tot3,   // (B,10)
    float* __restrict__ out)          // (B,10) f32
{
    const int b = blockIdx.x;
    const int tid = threadIdx.x;
    __shared__ float scale3[10], integ[10], red2[2];
    if (tid < 10) {
        float s = 0.f;
        for (int bb = 0; bb < BATCH; ++bb) s += tot3[bb*10 + tid];
        scale3[tid] = 1.f / (s / (float)BATCH + EPS_F);
    }
    __syncthreads();
    if (tid < 10) {
        float s = 0.f;
        const float* base = sel3 + (size_t)((b*10 + tid)*5)*7;
        for (int kk = 0; kk < 5; ++kk) {
            const float* c = base + kk*7;
            const float det = c[3]*c[6] - c[4]*c[5];
            s += c[0] * scale3[tid] * TWO_PI_F * sqrtf(fmaxf(det, EPS_F));
        }
        integ[tid] = sane(s);
    }
    __syncthreads();
    if (tid == 0) {
        float m = -1e30f;
        for (int l = 0; l < 10; ++l) m = fmaxf(m, integ[l]);
        float ss = 0.f;
        for (int l = 0; l < 10; ++l) ss += __expf(integ[l] - m);
        red2[0] = m; red2[1] = logf(ss);
    }
    __syncthreads();
    if (tid < 10) out[b*10 + tid] = integ[tid] - red2[0] - red2[1];
}

extern "C" void kernel_launch(void* const* d_in, const int* in_sizes, int n_in,
                              void* d_out, int out_size, void* d_ws, size_t ws_size,
                              hipStream_t stream)
{
    const float* in_x = (const float*)d_in[0];
    const float* k1   = (const float*)d_in[1];
    const float* k2   = (const float*)d_in[2];
    const float* k3   = (const float*)d_in[3];
    const float* b1   = (const float*)d_in[4];
    const float* b2   = (const float*)d_in[5];
    const float* b3   = (const float*)d_in[6];
    float* out = (float*)d_out;   // reference output dtype is float32

    float* ws = (float*)d_ws;
    float* sel1 = ws;                  // 32*5*25*7  = 28000 floats
    float* tot1 = ws + 28000;          // 160
    float* sel2 = ws + 28160;          // 32*6*12*7  = 16128
    float* tot2 = ws + 44288;          // 192
    float* sel3 = ws + 44480;          // 32*10*5*7  = 11200
    float* tot3 = ws + 55680;          // 320  (total ~224 KB)

    // Layer 1 (unified image, warms I-cache): TPG=64(log2=6), G=16, CHUNK=20.
    layer_unified<<<BATCH*5, 1024, 0, stream>>>(
        in_x, nullptr, nullptr, k1, b1, sel1, tot1,
        5, 1, 64, 5, 320, 25, 6, 16, 20, 20, 64, 1);
    // Layer 2 (SAME code bytes -> warm I-lines): TPG=128(log2=7), G=8,
    // CHUNK=79, CHUNKP=80 (one zero pad row per group, bit-neutral).
    layer_unified<<<BATCH*6, 1024, 0, stream>>>(
        nullptr, sel1, tot1, k2, b2, sel2, tot2,
        6, 5, 25, 5, 625, 12, 7, 8, 79, 80, 125, 0);
    // Layer 3 (CONTROL, old KP=6 template): 360 comps, keep 5. TPG=64, G=12.
    layer_kernel<10, 6, 12, 5, 360, 5, 6, 64, 12, false><<<BATCH*10, 768, 0, stream>>>(
        nullptr, sel2, tot2, k3, b3, sel3, tot3);
    // Final: batchnorm + integrate + log_softmax.
    final_kernel<<<BATCH, 64, 0, stream>>>(sel3, tot3, out);
}